// Round 14
// baseline (162.462 us; speedup 1.0000x reference)
//
#include <hip/hip_runtime.h>

// PointTransformerLayer fused kernel (MI355X / gfx950) — round 24
//
// Math (identical to R21/R23, absmax 0.06445312, bit-identical j-order):
//   relu1 = relu(aI_i - a_j)            aI = pos@pW1 + pb1, a = pos@pW1
//   S1    = [relu1 | -k_j] @ [[W_pa],[aW1]] + (q_i@aW1 + c)   (K=128, fp8)
//   H     = relu(S1);  simL2 = H @ (aW2*log2e)
//   rpe   = relu1 @ pW2 (bf16); vv = (v+pb2)_j + rpe
//   out_i[d] = sum_j 2^simL2 * vv / sum_j 2^simL2
//
// R24 = R23 (89.9us) restructured to J-TILE 64 (4 subs x 16 j, 16 iters):
//   R23 showed occupancy is conclusively register-file-capped at 2
//   blocks/CU (the (256,3) bound was a no-op: VGPR 84 arch unchanged,
//   occupancy 24-25%).  Remaining slack: ~18% neither-pipe-busy = the
//   per-iter barrier drain.  j64 halves barriers (33 -> 17) and loop
//   overhead while keeping per-j work identical; LDS 69.6KB (2 blocks/CU
//   unchanged; R19 proved >64KB static LDS works).  num/den accumulation
//   order preserved EXACTLY -> bit-identical, absmax 0.06445312.
//   Spill tripwire: WRITE_SIZE ~256KB.  If neutral -> revert R23, terminal.

typedef float f32x4 __attribute__((ext_vector_type(4)));
typedef int   i32x8 __attribute__((ext_vector_type(8)));
using sh8 = __attribute__((ext_vector_type(8))) short;  // 8 bf16 (4 VGPRs)

static constexpr int NPTS = 1024;

#if __has_builtin(__builtin_amdgcn_exp2f)
#define EXP2(x) __builtin_amdgcn_exp2f(x)
#else
#define EXP2(x) exp2f(x)
#endif

// ---- ws layout (bytes) ----
static constexpr size_t BEXT8_OFF = 0;       // fp8 B_ext frags: 16*64*32 = 32768 B
static constexpr size_t AW2F_OFF = 32768;    // fp8 aW2 frags: 16384 B
static constexpr size_t PW2F_OFF = 49152;    // pW2 bf16 frags: 8192 B
static constexpr size_t CARR_OFF = 57344;    // 256 f32 = 1024 B
static constexpr size_t AI_OFF   = 58368;    // 1024*64 f32 (+pb1)      = 262144 B
static constexpr size_t VPT_OFF  = 320512;   // 64*1024 f32 (v+pb2, T)  = 262144 B
static constexpr size_t AJ_OFF   = 582656;   // 1024*64 bf16            = 131072 B
static constexpr size_t KN8_OFF  = 713728;   // 1024*64 fp8 (-k)        = 65536 B
static constexpr size_t QA_OFF   = 779264;   // 1024*256 f32 (q@aW1)    = 1048576 B

__device__ __forceinline__ unsigned short f2b_rne(float f) {
    unsigned u = __float_as_uint(f);
    u += 0x7fffu + ((u >> 16) & 1u);
    return (unsigned short)(u >> 16);
}
// trunc-pack two f32 into bf16x2 — single v_perm_b32
__device__ __forceinline__ unsigned pk2(float lo, float hi) {
    return __builtin_amdgcn_perm(__float_as_uint(hi), __float_as_uint(lo), 0x07060302);
}
__device__ __forceinline__ float b2f(unsigned short s) {
    return __uint_as_float(((unsigned)s) << 16);
}
__device__ __forceinline__ unsigned char f2fp8(float v) {
    return (unsigned char)(__builtin_amdgcn_cvt_pk_fp8_f32(v, 0.f, 0, false) & 0xff);
}
__device__ __forceinline__ unsigned pk4fp8(float a, float b, float c, float d) {
    int r = __builtin_amdgcn_cvt_pk_fp8_f32(a, b, 0, false);
    r = __builtin_amdgcn_cvt_pk_fp8_f32(c, d, r, true);
    return (unsigned)r;
}
__device__ __forceinline__ i32x8 ld32B(const void* p) {
    const uint4 a = ((const uint4*)p)[0];
    const uint4 b = ((const uint4*)p)[1];
    i32x8 r;
    r[0] = a.x; r[1] = a.y; r[2] = a.z; r[3] = a.w;
    r[4] = b.x; r[5] = b.y; r[6] = b.z; r[7] = b.w;
    return r;
}

// ---------------- combined prep (identical to R21/R23) ----------------
// blocks: [0,128) bext8 | [128,192) aw2f8 | [192,208) pw2f | 208 cArr
//         [209,465) points (4/blk) | [465,1489) QA (1 i/blk)
__global__ void prep_all(const float* __restrict__ x, const float* __restrict__ pos,
                         const float* __restrict__ Wq, const float* __restrict__ Wk,
                         const float* __restrict__ Wv, const float* __restrict__ pW1,
                         const float* __restrict__ pb1, const float* __restrict__ pW2,
                         const float* __restrict__ pb2, const float* __restrict__ aW1,
                         const float* __restrict__ ab1, const float* __restrict__ aW2,
                         unsigned char* __restrict__ bext8, unsigned char* __restrict__ aw2f8,
                         unsigned short* __restrict__ pw2f, float* __restrict__ cArr,
                         unsigned char* __restrict__ kN8, float* __restrict__ vPT,
                         float* __restrict__ aI, unsigned short* __restrict__ aJ,
                         float* __restrict__ qa)
{
    __shared__ float s1[4][64];
    __shared__ float s2[4][64];
    const int b = blockIdx.x;
    if (b < 128) {
        // fp8 B_ext frags for G1 mfma_scale 16x16x128.
        const int r = b * 256 + threadIdx.x;  // < 32768
        const int frag = r >> 11, lane = (r >> 5) & 63, e = r & 31;
        const int w = frag >> 2, nt = frag & 3;
        const int tl = lane & 15, qq = lane >> 4;
        const int k = qq * 32 + e;
        const int t = 64 * w + 16 * nt + tl;
        float val;
        if (k < 64) {
            float s = 0.f;
            for (int d = 0; d < 64; ++d) s = fmaf(pW2[k * 64 + d], aW1[d * 256 + t], s);
            val = s;
        } else {
            val = aW1[(k - 64) * 256 + t];
        }
        bext8[r] = f2fp8(val);
    } else if (b < 192) {
        // aW2*log2e fp8 frags for G2 mfma_scale 16x16x128 (R9-verified)
        const int r = (b - 128) * 256 + threadIdx.x;  // < 16384
        const int e = r & 31, lane = (r >> 5) & 63, wsl = (r >> 11) & 3, kb = r >> 13;
        const int q = lane >> 4, dl = lane & 15;
        const int kp = kb * 128 + q * 32 + e;
        const int t = 64 * (kp >> 6) + 16 * (kp & 3) + ((kp >> 2) & 15);
        const int d = 16 * wsl + dl;
        aw2f8[r] = f2fp8(aW2[t * 64 + d] * 1.4426950408889634f);
    } else if (b < 208) {
        // pW2 bf16 frags for G3 (R2-verified)
        const int r = (b - 192) * 256 + threadIdx.x;  // < 4096
        const int k = r >> 6, d = r & 63;
        const int kc = k >> 5, kl = k & 31, qq = kl >> 3, e = kl & 7;
        const int nt = d >> 4, dl = d & 15;
        pw2f[(((size_t)(kc * 4 + nt) * 64) + (qq * 16 + dl)) * 8 + e] = f2b_rne(pW2[k * 64 + d]);
    } else if (b == 208) {
        const int t = threadIdx.x;
        float s = ab1[t];
        for (int d = 0; d < 64; ++d) s = fmaf(pb2[d], aW1[d * 256 + t], s);
        cArr[t] = s;
    } else if (b < 465) {
        // per-point prep: k(fp8), v, aI, aJ — 4 points per block
        const int t = threadIdx.x, sub = t >> 6, d = t & 63;
        const int i = (b - 209) * 4 + sub;
        s1[sub][d] = x[i * 64 + d];
        __syncthreads();
        float k = 0.f, v = 0.f;
        for (int e = 0; e < 64; ++e) {
            const float xe = s1[sub][e];
            k = fmaf(xe, Wk[e * 64 + d], k);
            v = fmaf(xe, Wv[e * 64 + d], v);
        }
        const float a = pos[i * 2] * pW1[d] + pos[i * 2 + 1] * pW1[64 + d];
        kN8[i * 64 + d] = f2fp8(-k);
        vPT[d * NPTS + i] = v + pb2[d];
        aI[i * 64 + d] = a + pb1[d];
        aJ[i * 64 + d] = f2b_rne(a);
    } else {
        // QA[i][t] = (x_i@Wq)@aW1, f32 (per-block-constant fold in main)
        const int i = b - 465, t = threadIdx.x;
        if (t < 64) s1[0][t] = x[i * 64 + t];
        __syncthreads();
        if (t < 64) {
            float s = 0.f;
            for (int e = 0; e < 64; ++e) s = fmaf(s1[0][e], Wq[e * 64 + t], s);
            s2[0][t] = s;
        }
        __syncthreads();
        float s = 0.f;
        for (int d = 0; d < 64; ++d) s = fmaf(s2[0][d], aW1[d * 256 + t], s);
        qa[(size_t)i * 256 + t] = s;
    }
}

// ---------------- main fused kernel: one block per query i, j-tile 64 ----------------
__global__ __launch_bounds__(256, 2) void ptl_main(
    const float* __restrict__ aI, const unsigned short* __restrict__ aJ,
    const unsigned char* __restrict__ kN8, const float* __restrict__ vPT,
    const unsigned char* __restrict__ bext8, const unsigned char* __restrict__ aw2f8,
    const unsigned short* __restrict__ pw2f, const float* __restrict__ cArr,
    const float* __restrict__ qa, float* __restrict__ out)
{
    const int i    = blockIdx.x;
    const int tid  = threadIdx.x;
    const int w    = tid >> 6;    // wave: t-slice [64w,64w+64) for G1, d-slice [16w,16w+16) for G2/G3
    const int lane = tid & 63;
    const int m    = lane & 15;
    const int q    = lane >> 4;

    // double-buffered LDS, 4 subs (j-tile 64):
    //   AfL (bf16 relu1 frags, G3): [buf][sub][half][lane] = 16 KB
    //   Af8 (fp8 A-tile, G1): [buf][sub][16 x 144]          = 18.4 KB
    //   Hs  (fp8 H, G2): [buf][sub][16 x 272]               = 34.8 KB  (69.6 KB total)
    __shared__ __align__(16) uint4 AfL[2][4][2][64];
    __shared__ __align__(16) unsigned char Af8[2][4][16 * 144];
    __shared__ __align__(16) unsigned char Hs[2][4][16 * 272];

    // constant B fragments
    i32x8 B8f[4];  // G1 fp8: [nt 0..3] for this wave's t-slice
#pragma unroll
    for (int nt = 0; nt < 4; ++nt)
        B8f[nt] = ld32B(bext8 + ((size_t)((4 * w + nt) * 64 + lane)) * 32);
    i32x8 W2f[2];  // G2 fp8: [kb 0..1], d-slice w
#pragma unroll
    for (int kb = 0; kb < 2; ++kb)
        W2f[kb] = ld32B(aw2f8 + ((size_t)((kb * 4 + w) * 64 + lane)) * 32);
    sh8 P2f[2];  // G3 bf16: [kc 0..1], d-slice w
#pragma unroll
    for (int kc = 0; kc < 2; ++kc)
        P2f[kc] = *(const sh8*)(pw2f + ((size_t)((kc * 4 + w) * 64 + lane)) * 8);

    float creg[4];  // c + QA_i (both constant over j)
#pragma unroll
    for (int nt = 0; nt < 4; ++nt)
        creg[nt] = cArr[64 * w + 16 * nt + m] + qa[(size_t)i * 256 + 64 * w + 16 * nt + m];

    // builder: wave w handles half h_ of subs sA and sA+2
    const int h_ = w & 1, sA = w >> 1;
    const unsigned short* bsrcA  = aJ  + m * 64 + h_ * 32 + q * 8;
    const unsigned char*  bsrcK8 = kN8 + m * 64 + h_ * 32 + q * 8;
    const float*          ibase  = aI + (size_t)i * 64 + h_ * 32 + q * 8;
    float iv[8];
    *(float4*)(iv)     = *(const float4*)(ibase);
    *(float4*)(iv + 4) = *(const float4*)(ibase + 4);

    // build one (sub, h_) task: relu1 bf16 (G3) + fp8 (G1) + kN fp8 copy
    auto build = [&](int buf, int s, const sh8& rawA, const uint2& rawK) {
        float t[8];
#pragma unroll
        for (int e = 0; e < 8; ++e)
            t[e] = fmaxf(iv[e] - b2f((unsigned short)rawA[e]), 0.f);
        uint4 pk;
        pk.x = pk2(t[0], t[1]); pk.y = pk2(t[2], t[3]);
        pk.z = pk2(t[4], t[5]); pk.w = pk2(t[6], t[7]);
        AfL[buf][s][h_][lane] = pk;
        uint2 f8;
        f8.x = pk4fp8(t[0], t[1], t[2], t[3]);
        f8.y = pk4fp8(t[4], t[5], t[6], t[7]);
        *(uint2*)(Af8[buf][s] + m * 144 + h_ * 32 + q * 8)      = f8;
        *(uint2*)(Af8[buf][s] + m * 144 + 64 + h_ * 32 + q * 8) = rawK;
    };

    // G1 for one sub: fp8 K=128 (4 mfma_scale) + H-write
    auto g1pass = [&](int buf, int s) {
        const i32x8 A8 = ld32B(Af8[buf][s] + m * 144 + 32 * q);
        f32x4 acc[4];
#pragma unroll
        for (int nt = 0; nt < 4; ++nt) {
            const f32x4 cv = {creg[nt], creg[nt], creg[nt], creg[nt]};
            acc[nt] = __builtin_amdgcn_mfma_scale_f32_16x16x128_f8f6f4(
                A8, B8f[nt], cv, 0, 0, 0, 127, 0, 127);
        }
        unsigned char* hw = Hs[buf][s] + (4 * q) * 272 + 64 * w + 4 * m;
#pragma unroll
        for (int r = 0; r < 4; ++r)
            *(unsigned*)(hw + r * 272) = pk4fp8(fmaxf(acc[0][r], 0.f), fmaxf(acc[1][r], 0.f),
                                                fmaxf(acc[2][r], 0.f), fmaxf(acc[3][r], 0.f));
    };

    // prologue: build tile 0 into buffer 0 (both tasks of this wave)
    {
        const sh8  rA0 = *(const sh8*)(bsrcA + (size_t)(16 * sA) * 64);
        const sh8  rA1 = *(const sh8*)(bsrcA + (size_t)(16 * (sA + 2)) * 64);
        const uint2 rK0 = *(const uint2*)(bsrcK8 + (size_t)(16 * sA) * 64);
        const uint2 rK1 = *(const uint2*)(bsrcK8 + (size_t)(16 * (sA + 2)) * 64);
        build(0, sA, rA0, rK0);
        build(0, sA + 2, rA1, rK1);
    }
    __syncthreads();

    float num = 0.f, den = 0.f;
    const f32x4 z4 = {0.f, 0.f, 0.f, 0.f};
    f32x4 aRp0 = z4, aRp1 = z4, aRp2 = z4, aRp3 = z4;  // per-sub G3 carries
    const float* vbase = vPT + (size_t)(16 * w + m) * NPTS;

    // G2+softmax for a sub pair (r-interleaved — preserves R21's j-order)
    auto g2pair = [&](const i32x8& h00, const i32x8& h01, const i32x8& h10,
                      const i32x8& h11, const f32x4& p0, const f32x4& p1) {
        f32x4 aS0 = z4, aS1 = z4;
        aS0 = __builtin_amdgcn_mfma_scale_f32_16x16x128_f8f6f4(h00, W2f[0], aS0, 0, 0, 0, 127, 0, 127);
        aS0 = __builtin_amdgcn_mfma_scale_f32_16x16x128_f8f6f4(h01, W2f[1], aS0, 0, 0, 0, 127, 0, 127);
        aS1 = __builtin_amdgcn_mfma_scale_f32_16x16x128_f8f6f4(h10, W2f[0], aS1, 0, 0, 0, 127, 0, 127);
        aS1 = __builtin_amdgcn_mfma_scale_f32_16x16x128_f8f6f4(h11, W2f[1], aS1, 0, 0, 0, 127, 0, 127);
#pragma unroll
        for (int r = 0; r < 4; ++r) {
            const float e0 = EXP2(aS0[r]);
            num = fmaf(e0, p0[r], num);
            den += e0;
            const float e1 = EXP2(aS1[r]);
            num = fmaf(e1, p1[r], num);
            den += e1;
        }
    };

    for (int n = 0; n < 16; ++n) {
        const int pb = n & 1, nb = pb ^ 1;
        const int j0 = n << 6;

        // next tile's raw global loads (this wave's two tasks), issued early
        sh8  rA0, rA1;
        uint2 rK0, rK1;
        if (n < 15) {
            rA0 = *(const sh8*)(bsrcA + (size_t)(j0 + 64 + 16 * sA) * 64);
            rA1 = *(const sh8*)(bsrcA + (size_t)(j0 + 64 + 16 * (sA + 2)) * 64);
            rK0 = *(const uint2*)(bsrcK8 + (size_t)(j0 + 64 + 16 * sA) * 64);
            rK1 = *(const uint2*)(bsrcK8 + (size_t)(j0 + 64 + 16 * (sA + 2)) * 64);
        }
        // v values (C-operand of G3), 4 subs
        const float4 vj0 = *(const float4*)(vbase + j0 + 4 * q);
        const float4 vj1 = *(const float4*)(vbase + j0 + 16 + 4 * q);
        const float4 vj2 = *(const float4*)(vbase + j0 + 32 + 4 * q);
        const float4 vj3 = *(const float4*)(vbase + j0 + 48 + 4 * q);

        // ---- G1 subs 0,1 ----
        g1pass(pb, 0);
        g1pass(pb, 1);

        // ---- deferred-G2 loads for subs 0,1 of tile n-1 (hidden under G1 subs 2,3) ----
        i32x8 ha0, ha1, hb0, hb1;
        if (n) {
            ha0 = ld32B(Hs[nb][0] + m * 272 + 0   + 32 * q);
            ha1 = ld32B(Hs[nb][0] + m * 272 + 128 + 32 * q);
            hb0 = ld32B(Hs[nb][1] + m * 272 + 0   + 32 * q);
            hb1 = ld32B(Hs[nb][1] + m * 272 + 128 + 32 * q);
        }

        // ---- G1 subs 2,3 ----
        g1pass(pb, 2);
        g1pass(pb, 3);

        // ---- deferred G2 subs 0,1 ----
        if (n) g2pair(ha0, ha1, hb0, hb1, aRp0, aRp1);

        // ---- deferred-G2 loads + compute for subs 2,3 ----
        if (n) {
            const i32x8 hc0 = ld32B(Hs[nb][2] + m * 272 + 0   + 32 * q);
            const i32x8 hc1 = ld32B(Hs[nb][2] + m * 272 + 128 + 32 * q);
            const i32x8 hd0 = ld32B(Hs[nb][3] + m * 272 + 0   + 32 * q);
            const i32x8 hd1 = ld32B(Hs[nb][3] + m * 272 + 128 + 32 * q);
            g2pair(hc0, hc1, hd0, hd1, aRp2, aRp3);
        }

        // ---- G3 (pre-barrier, bf16): rpe + v for tile n, carried to n+1 ----
        {
            const f32x4 vc0 = {vj0.x, vj0.y, vj0.z, vj0.w};
            const sh8 Ak0 = *(const sh8*)&AfL[pb][0][0][lane];
            const sh8 Ak1 = *(const sh8*)&AfL[pb][0][1][lane];
            f32x4 aR = __builtin_amdgcn_mfma_f32_16x16x32_bf16(Ak0, P2f[0], vc0, 0, 0, 0);
            aRp0 = __builtin_amdgcn_mfma_f32_16x16x32_bf16(Ak1, P2f[1], aR, 0, 0, 0);
        }
        {
            const f32x4 vc1 = {vj1.x, vj1.y, vj1.z, vj1.w};
            const sh8 Ak0 = *(const sh8*)&AfL[pb][1][0][lane];
            const sh8 Ak1 = *(const sh8*)&AfL[pb][1][1][lane];
            f32x4 aR = __builtin_amdgcn_mfma_f32_16x16x32_bf16(Ak0, P2f[0], vc1, 0, 0, 0);
            aRp1 = __builtin_amdgcn_mfma_f32_16x16x32_bf16(Ak1, P2f[1], aR, 0, 0, 0);
        }
        {
            const f32x4 vc2 = {vj2.x, vj2.y, vj2.z, vj2.w};
            const sh8 Ak0 = *(const sh8*)&AfL[pb][2][0][lane];
            const sh8 Ak1 = *(const sh8*)&AfL[pb][2][1][lane];
            f32x4 aR = __builtin_amdgcn_mfma_f32_16x16x32_bf16(Ak0, P2f[0], vc2, 0, 0, 0);
            aRp2 = __builtin_amdgcn_mfma_f32_16x16x32_bf16(Ak1, P2f[1], aR, 0, 0, 0);
        }
        {
            const f32x4 vc3 = {vj3.x, vj3.y, vj3.z, vj3.w};
            const sh8 Ak0 = *(const sh8*)&AfL[pb][3][0][lane];
            const sh8 Ak1 = *(const sh8*)&AfL[pb][3][1][lane];
            f32x4 aR = __builtin_amdgcn_mfma_f32_16x16x32_bf16(Ak0, P2f[0], vc3, 0, 0, 0);
            aRp3 = __builtin_amdgcn_mfma_f32_16x16x32_bf16(Ak1, P2f[1], aR, 0, 0, 0);
        }

        // build next tile's frags (this wave's two tasks)
        if (n < 15) {
            build(nb, sA, rA0, rK0);
            build(nb, sA + 2, rA1, rK1);
        }

        __syncthreads();  // publishes Hs[pb][*] (G2 next iter), AfL/Af8[nb][*]
    }

    // ---- epilogue: deferred G2 for the final tile (pb=1, published above) ----
    {
        const i32x8 ha0 = ld32B(Hs[1][0] + m * 272 + 0   + 32 * q);
        const i32x8 ha1 = ld32B(Hs[1][0] + m * 272 + 128 + 32 * q);
        const i32x8 hb0 = ld32B(Hs[1][1] + m * 272 + 0   + 32 * q);
        const i32x8 hb1 = ld32B(Hs[1][1] + m * 272 + 128 + 32 * q);
        g2pair(ha0, ha1, hb0, hb1, aRp0, aRp1);
        const i32x8 hc0 = ld32B(Hs[1][2] + m * 272 + 0   + 32 * q);
        const i32x8 hc1 = ld32B(Hs[1][2] + m * 272 + 128 + 32 * q);
        const i32x8 hd0 = ld32B(Hs[1][3] + m * 272 + 0   + 32 * q);
        const i32x8 hd1 = ld32B(Hs[1][3] + m * 272 + 128 + 32 * q);
        g2pair(hc0, hc1, hd0, hd1, aRp2, aRp3);
    }

    // reduce the 4 quad-partials (lanes m, m+16, m+32, m+48)
    num += __shfl_xor(num, 16);
    num += __shfl_xor(num, 32);
    den += __shfl_xor(den, 16);
    den += __shfl_xor(den, 32);
    if (q == 0) out[i * 64 + 16 * w + m] = num / den;
}

extern "C" void kernel_launch(void* const* d_in, const int* in_sizes, int n_in,
                              void* d_out, int out_size, void* d_ws, size_t ws_size,
                              hipStream_t stream) {
    const float* x   = (const float*)d_in[0];
    const float* pos = (const float*)d_in[1];
    const float* Wq  = (const float*)d_in[2];
    const float* Wk  = (const float*)d_in[3];
    const float* Wv  = (const float*)d_in[4];
    const float* pW1 = (const float*)d_in[5];
    const float* pb1 = (const float*)d_in[6];
    const float* pW2 = (const float*)d_in[7];
    const float* pb2 = (const float*)d_in[8];
    const float* aW1 = (const float*)d_in[9];
    const float* ab1 = (const float*)d_in[10];
    const float* aW2 = (const float*)d_in[11];
    // d_in[12] = ab2: constant over j -> cancels in per-channel softmax, unused.

    char* ws = (char*)d_ws;
    unsigned char*  bext8 = (unsigned char*)(ws + BEXT8_OFF);
    unsigned char*  aw2f8 = (unsigned char*)(ws + AW2F_OFF);
    unsigned short* pw2f  = (unsigned short*)(ws + PW2F_OFF);
    float*          cArr  = (float*)(ws + CARR_OFF);
    float*          aIa   = (float*)(ws + AI_OFF);
    float*          vPTa  = (float*)(ws + VPT_OFF);
    unsigned short* aJa   = (unsigned short*)(ws + AJ_OFF);
    unsigned char*  kN8a  = (unsigned char*)(ws + KN8_OFF);
    float*          qaA   = (float*)(ws + QA_OFF);

    prep_all<<<1489, 256, 0, stream>>>(x, pos, Wq, Wk, Wv, pW1, pb1, pW2, pb2, aW1, ab1, aW2,
                                       bext8, aw2f8, pw2f, cArr, kN8a, vPTa, aIa, aJa, qaA);
    ptl_main<<<NPTS, 256, 0, stream>>>(aIa, aJa, kN8a, vPTa, bext8, aw2f8, pw2f, cArr, qaA,
                                       (float*)d_out);
}

// Round 15
// 159.392 us; speedup vs baseline: 1.0193x; 1.0193x over previous
//
#include <hip/hip_runtime.h>

// PointTransformerLayer fused kernel (MI355X / gfx950) — round 25 FINAL
// (= R23/R21 fp8-G1 kernel, the session best: ptl_main 89.9us, total
//  158.1us, absmax 0.06445312.  R24's j64 restructure regressed 89.9->96.0
//  (+24 VGPR, occupancy 24.5->19%) — reverted per pre-committed rule.)
//
// Math:
//   relu1 = relu(aI_i - a_j)            aI = pos@pW1 + pb1, a = pos@pW1
//   S1    = [relu1 | -k_j] @ [[W_pa],[aW1]] + (q_i@aW1 + c)   (K=128, fp8
//           e4m3 via mfma_scale_f32_16x16x128, unit scales)
//   H     = relu(S1);  simL2 = H @ (aW2*log2e)   (ab2 softmax-invariant)
//   rpe   = relu1 @ pW2 (bf16); vv = (v+pb2)_j + rpe
//   out_i[d] = sum_j 2^simL2 * vv / sum_j 2^simL2
//
// Session conclusions (R10->R25, 183.2 -> 158.1us total):
//   WINS: G2 software-pipeline (-3us, R14); q-k builder deletion via
//   QA-fold + kN verbatim copy (-8us, R20); G1 bf16->fp8 K=128 (-21.6us,
//   R21).  NULLS/REGRESSIONS, each diagnostic: forced occupancy spills
//   (R12/R13/R23: register-file-capped at 2 blocks/CU); 2-query ILP null
//   (R19: throughput-bound); ka-prefetch schedule motion erased by
//   compiler (R15-17); setprio null (R18); j64 barrier-halving
//   net-negative (R24).  Remaining VALU stream is algorithm-intrinsic.

typedef float f32x4 __attribute__((ext_vector_type(4)));
typedef int   i32x8 __attribute__((ext_vector_type(8)));
using sh8 = __attribute__((ext_vector_type(8))) short;  // 8 bf16 (4 VGPRs)

static constexpr int NPTS = 1024;

#if __has_builtin(__builtin_amdgcn_exp2f)
#define EXP2(x) __builtin_amdgcn_exp2f(x)
#else
#define EXP2(x) exp2f(x)
#endif

// ---- ws layout (bytes) ----
static constexpr size_t BEXT8_OFF = 0;       // fp8 B_ext frags: 16*64*32 = 32768 B
static constexpr size_t AW2F_OFF = 32768;    // fp8 aW2 frags: 16384 B
static constexpr size_t PW2F_OFF = 49152;    // pW2 bf16 frags: 8192 B
static constexpr size_t CARR_OFF = 57344;    // 256 f32 = 1024 B
static constexpr size_t AI_OFF   = 58368;    // 1024*64 f32 (+pb1)      = 262144 B
static constexpr size_t VPT_OFF  = 320512;   // 64*1024 f32 (v+pb2, T)  = 262144 B
static constexpr size_t AJ_OFF   = 582656;   // 1024*64 bf16            = 131072 B
static constexpr size_t KN8_OFF  = 713728;   // 1024*64 fp8 (-k)        = 65536 B
static constexpr size_t QA_OFF   = 779264;   // 1024*256 f32 (q@aW1)    = 1048576 B

__device__ __forceinline__ unsigned short f2b_rne(float f) {
    unsigned u = __float_as_uint(f);
    u += 0x7fffu + ((u >> 16) & 1u);
    return (unsigned short)(u >> 16);
}
// trunc-pack two f32 into bf16x2 — single v_perm_b32
__device__ __forceinline__ unsigned pk2(float lo, float hi) {
    return __builtin_amdgcn_perm(__float_as_uint(hi), __float_as_uint(lo), 0x07060302);
}
__device__ __forceinline__ float b2f(unsigned short s) {
    return __uint_as_float(((unsigned)s) << 16);
}
__device__ __forceinline__ unsigned char f2fp8(float v) {
    return (unsigned char)(__builtin_amdgcn_cvt_pk_fp8_f32(v, 0.f, 0, false) & 0xff);
}
__device__ __forceinline__ unsigned pk4fp8(float a, float b, float c, float d) {
    int r = __builtin_amdgcn_cvt_pk_fp8_f32(a, b, 0, false);
    r = __builtin_amdgcn_cvt_pk_fp8_f32(c, d, r, true);
    return (unsigned)r;
}
__device__ __forceinline__ i32x8 ld32B(const void* p) {
    const uint4 a = ((const uint4*)p)[0];
    const uint4 b = ((const uint4*)p)[1];
    i32x8 r;
    r[0] = a.x; r[1] = a.y; r[2] = a.z; r[3] = a.w;
    r[4] = b.x; r[5] = b.y; r[6] = b.z; r[7] = b.w;
    return r;
}

// ---------------- combined prep ----------------
// blocks: [0,128) bext8 | [128,192) aw2f8 | [192,208) pw2f | 208 cArr
//         [209,465) points (4/blk) | [465,1489) QA (1 i/blk)
__global__ void prep_all(const float* __restrict__ x, const float* __restrict__ pos,
                         const float* __restrict__ Wq, const float* __restrict__ Wk,
                         const float* __restrict__ Wv, const float* __restrict__ pW1,
                         const float* __restrict__ pb1, const float* __restrict__ pW2,
                         const float* __restrict__ pb2, const float* __restrict__ aW1,
                         const float* __restrict__ ab1, const float* __restrict__ aW2,
                         unsigned char* __restrict__ bext8, unsigned char* __restrict__ aw2f8,
                         unsigned short* __restrict__ pw2f, float* __restrict__ cArr,
                         unsigned char* __restrict__ kN8, float* __restrict__ vPT,
                         float* __restrict__ aI, unsigned short* __restrict__ aJ,
                         float* __restrict__ qa)
{
    __shared__ float s1[4][64];
    __shared__ float s2[4][64];
    const int b = blockIdx.x;
    if (b < 128) {
        // fp8 B_ext frags for G1 mfma_scale 16x16x128.
        const int r = b * 256 + threadIdx.x;  // < 32768
        const int frag = r >> 11, lane = (r >> 5) & 63, e = r & 31;
        const int w = frag >> 2, nt = frag & 3;
        const int tl = lane & 15, qq = lane >> 4;
        const int k = qq * 32 + e;
        const int t = 64 * w + 16 * nt + tl;
        float val;
        if (k < 64) {
            float s = 0.f;
            for (int d = 0; d < 64; ++d) s = fmaf(pW2[k * 64 + d], aW1[d * 256 + t], s);
            val = s;
        } else {
            val = aW1[(k - 64) * 256 + t];
        }
        bext8[r] = f2fp8(val);
    } else if (b < 192) {
        // aW2*log2e fp8 frags for G2 mfma_scale 16x16x128 (R9-verified)
        const int r = (b - 128) * 256 + threadIdx.x;  // < 16384
        const int e = r & 31, lane = (r >> 5) & 63, wsl = (r >> 11) & 3, kb = r >> 13;
        const int q = lane >> 4, dl = lane & 15;
        const int kp = kb * 128 + q * 32 + e;
        const int t = 64 * (kp >> 6) + 16 * (kp & 3) + ((kp >> 2) & 15);
        const int d = 16 * wsl + dl;
        aw2f8[r] = f2fp8(aW2[t * 64 + d] * 1.4426950408889634f);
    } else if (b < 208) {
        // pW2 bf16 frags for G3 (R2-verified)
        const int r = (b - 192) * 256 + threadIdx.x;  // < 4096
        const int k = r >> 6, d = r & 63;
        const int kc = k >> 5, kl = k & 31, qq = kl >> 3, e = kl & 7;
        const int nt = d >> 4, dl = d & 15;
        pw2f[(((size_t)(kc * 4 + nt) * 64) + (qq * 16 + dl)) * 8 + e] = f2b_rne(pW2[k * 64 + d]);
    } else if (b == 208) {
        const int t = threadIdx.x;
        float s = ab1[t];
        for (int d = 0; d < 64; ++d) s = fmaf(pb2[d], aW1[d * 256 + t], s);
        cArr[t] = s;
    } else if (b < 465) {
        // per-point prep: k(fp8), v, aI, aJ — 4 points per block
        const int t = threadIdx.x, sub = t >> 6, d = t & 63;
        const int i = (b - 209) * 4 + sub;
        s1[sub][d] = x[i * 64 + d];
        __syncthreads();
        float k = 0.f, v = 0.f;
        for (int e = 0; e < 64; ++e) {
            const float xe = s1[sub][e];
            k = fmaf(xe, Wk[e * 64 + d], k);
            v = fmaf(xe, Wv[e * 64 + d], v);
        }
        const float a = pos[i * 2] * pW1[d] + pos[i * 2 + 1] * pW1[64 + d];
        kN8[i * 64 + d] = f2fp8(-k);
        vPT[d * NPTS + i] = v + pb2[d];
        aI[i * 64 + d] = a + pb1[d];
        aJ[i * 64 + d] = f2b_rne(a);
    } else {
        // QA[i][t] = (x_i@Wq)@aW1, f32 (per-block-constant fold in main)
        const int i = b - 465, t = threadIdx.x;
        if (t < 64) s1[0][t] = x[i * 64 + t];
        __syncthreads();
        if (t < 64) {
            float s = 0.f;
            for (int e = 0; e < 64; ++e) s = fmaf(s1[0][e], Wq[e * 64 + t], s);
            s2[0][t] = s;
        }
        __syncthreads();
        float s = 0.f;
        for (int d = 0; d < 64; ++d) s = fmaf(s2[0][d], aW1[d * 256 + t], s);
        qa[(size_t)i * 256 + t] = s;
    }
}

// ---------------- main fused kernel: one block per query i, j-tile 32 ----------------
__global__ __launch_bounds__(256, 2) void ptl_main(
    const float* __restrict__ aI, const unsigned short* __restrict__ aJ,
    const unsigned char* __restrict__ kN8, const float* __restrict__ vPT,
    const unsigned char* __restrict__ bext8, const unsigned char* __restrict__ aw2f8,
    const unsigned short* __restrict__ pw2f, const float* __restrict__ cArr,
    const float* __restrict__ qa, float* __restrict__ out)
{
    const int i    = blockIdx.x;
    const int tid  = threadIdx.x;
    const int w    = tid >> 6;    // wave: t-slice [64w,64w+64) for G1, d-slice [16w,16w+16) for G2/G3
    const int lane = tid & 63;
    const int m    = lane & 15;
    const int q    = lane >> 4;

    // double-buffered LDS:
    //   AfL (bf16 relu1 frags, G3 only): [buf][sub][half][lane] = 8 KB
    //   Af8 (fp8 A-tile, G1): [buf][sub][16 rows x 144 stride]  = 9.2 KB
    //   Hs  (fp8 H, G2): stride 272                              = 17.4 KB
    __shared__ __align__(16) uint4 AfL[2][2][2][64];
    __shared__ __align__(16) unsigned char Af8[2][2][16 * 144];
    __shared__ __align__(16) unsigned char Hs[2][2][16 * 272];

    // constant B fragments
    i32x8 B8f[4];  // G1 fp8: [nt 0..3] for this wave's t-slice
#pragma unroll
    for (int nt = 0; nt < 4; ++nt)
        B8f[nt] = ld32B(bext8 + ((size_t)((4 * w + nt) * 64 + lane)) * 32);
    i32x8 W2f[2];  // G2 fp8: [kb 0..1], d-slice w
#pragma unroll
    for (int kb = 0; kb < 2; ++kb)
        W2f[kb] = ld32B(aw2f8 + ((size_t)((kb * 4 + w) * 64 + lane)) * 32);
    sh8 P2f[2];  // G3 bf16: [kc 0..1], d-slice w
#pragma unroll
    for (int kc = 0; kc < 2; ++kc)
        P2f[kc] = *(const sh8*)(pw2f + ((size_t)((kc * 4 + w) * 64 + lane)) * 8);

    float creg[4];  // c + QA_i (both constant over j)
#pragma unroll
    for (int nt = 0; nt < 4; ++nt)
        creg[nt] = cArr[64 * w + 16 * nt + m] + qa[(size_t)i * 256 + 64 * w + 16 * nt + m];

    // builder task: wave w = (sub s_, half h_).  Builds relu1 (bf16 for G3,
    // fp8 for G1) for k-chunk h_, and copies fp8 kN into kpos 64+32h_.
    const int s_ = w >> 1, h_ = w & 1;
    const unsigned short* bsrcA  = aJ  + m * 64 + h_ * 32 + q * 8;
    const unsigned char*  bsrcK8 = kN8 + m * 64 + h_ * 32 + q * 8;
    const float*          ibase  = aI + (size_t)i * 64 + h_ * 32 + q * 8;
    float iv[8];
    *(float4*)(iv)     = *(const float4*)(ibase);
    *(float4*)(iv + 4) = *(const float4*)(ibase + 4);

    // prologue: build tile 0 into buffer 0
    {
        const sh8  rawA  = *(const sh8*)(bsrcA + (size_t)(16 * s_) * 64);
        const uint2 rawK = *(const uint2*)(bsrcK8 + (size_t)(16 * s_) * 64);
        float t[8];
#pragma unroll
        for (int e = 0; e < 8; ++e)
            t[e] = fmaxf(iv[e] - b2f((unsigned short)rawA[e]), 0.f);
        uint4 pk;
        pk.x = pk2(t[0], t[1]); pk.y = pk2(t[2], t[3]);
        pk.z = pk2(t[4], t[5]); pk.w = pk2(t[6], t[7]);
        AfL[0][s_][h_][lane] = pk;
        uint2 f8;
        f8.x = pk4fp8(t[0], t[1], t[2], t[3]);
        f8.y = pk4fp8(t[4], t[5], t[6], t[7]);
        *(uint2*)(Af8[0][s_] + m * 144 + h_ * 32 + q * 8)      = f8;
        *(uint2*)(Af8[0][s_] + m * 144 + 64 + h_ * 32 + q * 8) = rawK;
    }
    __syncthreads();

    float num = 0.f, den = 0.f;
    const f32x4 z4 = {0.f, 0.f, 0.f, 0.f};
    f32x4 aRp0 = z4, aRp1 = z4;   // previous tile's G3 results (pipeline carry)
    const float* vbase = vPT + (size_t)(16 * w + m) * NPTS;

    for (int n = 0; n < 32; ++n) {
        const int pb = n & 1, nb = pb ^ 1;
        const int j0 = n << 5;

        // next tile's raw global loads (this wave's sub/half), issued early
        sh8  rawA;
        uint2 rawK;
        if (n < 31) {
            rawA = *(const sh8*)(bsrcA + (size_t)(j0 + 32 + 16 * s_) * 64);
            rawK = *(const uint2*)(bsrcK8 + (size_t)(j0 + 32 + 16 * s_) * 64);
        }
        // v values for own tile (C-operand of G3)
        const float4 vj0 = *(const float4*)(vbase + j0 + 4 * q);
        const float4 vj1 = *(const float4*)(vbase + j0 + 16 + 4 * q);

        // ---- sub 0: G1 fp8 K=128 (4 mfma_scale) + H-write ----
        {
            const i32x8 A8 = ld32B(Af8[pb][0] + m * 144 + 32 * q);
            f32x4 acc[4];
#pragma unroll
            for (int nt = 0; nt < 4; ++nt) {
                const f32x4 cv = {creg[nt], creg[nt], creg[nt], creg[nt]};
                acc[nt] = __builtin_amdgcn_mfma_scale_f32_16x16x128_f8f6f4(
                    A8, B8f[nt], cv, 0, 0, 0, 127, 0, 127);
            }
            unsigned char* hw = Hs[pb][0] + (4 * q) * 272 + 64 * w + 4 * m;
#pragma unroll
            for (int r = 0; r < 4; ++r)
                *(unsigned*)(hw + r * 272) = pk4fp8(fmaxf(acc[0][r], 0.f), fmaxf(acc[1][r], 0.f),
                                                   fmaxf(acc[2][r], 0.f), fmaxf(acc[3][r], 0.f));
        }

        // ---- deferred-G2 LDS loads for tile n-1 (Hs[nb], published last barrier) ----
        i32x8 h00, h01, h10, h11;
        if (n) {
            h00 = ld32B(Hs[nb][0] + m * 272 + 0   + 32 * q);
            h01 = ld32B(Hs[nb][0] + m * 272 + 128 + 32 * q);
            h10 = ld32B(Hs[nb][1] + m * 272 + 0   + 32 * q);
            h11 = ld32B(Hs[nb][1] + m * 272 + 128 + 32 * q);
        }

        // ---- sub 1: G1 fp8 + H-write ----
        {
            const i32x8 A8 = ld32B(Af8[pb][1] + m * 144 + 32 * q);
            f32x4 acc[4];
#pragma unroll
            for (int nt = 0; nt < 4; ++nt) {
                const f32x4 cv = {creg[nt], creg[nt], creg[nt], creg[nt]};
                acc[nt] = __builtin_amdgcn_mfma_scale_f32_16x16x128_f8f6f4(
                    A8, B8f[nt], cv, 0, 0, 0, 127, 0, 127);
            }
            unsigned char* hw = Hs[pb][1] + (4 * q) * 272 + 64 * w + 4 * m;
#pragma unroll
            for (int r = 0; r < 4; ++r)
                *(unsigned*)(hw + r * 272) = pk4fp8(fmaxf(acc[0][r], 0.f), fmaxf(acc[1][r], 0.f),
                                                   fmaxf(acc[2][r], 0.f), fmaxf(acc[3][r], 0.f));
        }

        // ---- G3 bf16 A-frag loads (AfL[pb]); latency hidden under G2 ----
        const sh8 A00 = *(const sh8*)&AfL[pb][0][0][lane];
        const sh8 A01 = *(const sh8*)&AfL[pb][0][1][lane];
        const sh8 A10 = *(const sh8*)&AfL[pb][1][0][lane];
        const sh8 A11 = *(const sh8*)&AfL[pb][1][1][lane];

        // ---- deferred G2 for tile n-1: simL2 + softmax accumulation ----
        if (n) {
            f32x4 aS0 = z4, aS1 = z4;
            aS0 = __builtin_amdgcn_mfma_scale_f32_16x16x128_f8f6f4(
                h00, W2f[0], aS0, 0, 0, 0, 127, 0, 127);
            aS0 = __builtin_amdgcn_mfma_scale_f32_16x16x128_f8f6f4(
                h01, W2f[1], aS0, 0, 0, 0, 127, 0, 127);
            aS1 = __builtin_amdgcn_mfma_scale_f32_16x16x128_f8f6f4(
                h10, W2f[0], aS1, 0, 0, 0, 127, 0, 127);
            aS1 = __builtin_amdgcn_mfma_scale_f32_16x16x128_f8f6f4(
                h11, W2f[1], aS1, 0, 0, 0, 127, 0, 127);
#pragma unroll
            for (int r = 0; r < 4; ++r) {
                const float e0 = EXP2(aS0[r]);
                num = fmaf(e0, aRp0[r], num);
                den += e0;
                const float e1 = EXP2(aS1[r]);
                num = fmaf(e1, aRp1[r], num);
                den += e1;
            }
        }

        // ---- G3 (pre-barrier, bf16): rpe + v for tile n, aR carried ----
        const f32x4 vc0 = {vj0.x, vj0.y, vj0.z, vj0.w};
        const f32x4 vc1 = {vj1.x, vj1.y, vj1.z, vj1.w};
        f32x4 aR0 = __builtin_amdgcn_mfma_f32_16x16x32_bf16(A00, P2f[0], vc0, 0, 0, 0);
        aR0 = __builtin_amdgcn_mfma_f32_16x16x32_bf16(A01, P2f[1], aR0, 0, 0, 0);
        f32x4 aR1 = __builtin_amdgcn_mfma_f32_16x16x32_bf16(A10, P2f[0], vc1, 0, 0, 0);
        aR1 = __builtin_amdgcn_mfma_f32_16x16x32_bf16(A11, P2f[1], aR1, 0, 0, 0);
        aRp0 = aR0;
        aRp1 = aR1;

        // build next tile's frags: relu1 (bf16+fp8) + fp8 kN copy
        if (n < 31) {
            float t[8];
#pragma unroll
            for (int e = 0; e < 8; ++e)
                t[e] = fmaxf(iv[e] - b2f((unsigned short)rawA[e]), 0.f);
            uint4 pk;
            pk.x = pk2(t[0], t[1]); pk.y = pk2(t[2], t[3]);
            pk.z = pk2(t[4], t[5]); pk.w = pk2(t[6], t[7]);
            AfL[nb][s_][h_][lane] = pk;
            uint2 f8;
            f8.x = pk4fp8(t[0], t[1], t[2], t[3]);
            f8.y = pk4fp8(t[4], t[5], t[6], t[7]);
            *(uint2*)(Af8[nb][s_] + m * 144 + h_ * 32 + q * 8)      = f8;
            *(uint2*)(Af8[nb][s_] + m * 144 + 64 + h_ * 32 + q * 8) = rawK;
        }

        __syncthreads();  // publishes Hs[pb][*] (G2 next iter), AfL/Af8[nb][*]
    }

    // ---- epilogue: deferred G2 for the final tile (buffer 1, published above) ----
    {
        f32x4 aS0 = z4, aS1 = z4;
        const i32x8 h00 = ld32B(Hs[1][0] + m * 272 + 0   + 32 * q);
        const i32x8 h01 = ld32B(Hs[1][0] + m * 272 + 128 + 32 * q);
        const i32x8 h10 = ld32B(Hs[1][1] + m * 272 + 0   + 32 * q);
        const i32x8 h11 = ld32B(Hs[1][1] + m * 272 + 128 + 32 * q);
        aS0 = __builtin_amdgcn_mfma_scale_f32_16x16x128_f8f6f4(
            h00, W2f[0], aS0, 0, 0, 0, 127, 0, 127);
        aS0 = __builtin_amdgcn_mfma_scale_f32_16x16x128_f8f6f4(
            h01, W2f[1], aS0, 0, 0, 0, 127, 0, 127);
        aS1 = __builtin_amdgcn_mfma_scale_f32_16x16x128_f8f6f4(
            h10, W2f[0], aS1, 0, 0, 0, 127, 0, 127);
        aS1 = __builtin_amdgcn_mfma_scale_f32_16x16x128_f8f6f4(
            h11, W2f[1], aS1, 0, 0, 0, 127, 0, 127);
#pragma unroll
        for (int r = 0; r < 4; ++r) {
            const float e0 = EXP2(aS0[r]);
            num = fmaf(e0, aRp0[r], num);
            den += e0;
            const float e1 = EXP2(aS1[r]);
            num = fmaf(e1, aRp1[r], num);
            den += e1;
        }
    }

    // reduce the 4 quad-partials (lanes m, m+16, m+32, m+48)
    num += __shfl_xor(num, 16);
    num += __shfl_xor(num, 32);
    den += __shfl_xor(den, 16);
    den += __shfl_xor(den, 32);
    if (q == 0) out[i * 64 + 16 * w + m] = num / den;
}

extern "C" void kernel_launch(void* const* d_in, const int* in_sizes, int n_in,
                              void* d_out, int out_size, void* d_ws, size_t ws_size,
                              hipStream_t stream) {
    const float* x   = (const float*)d_in[0];
    const float* pos = (const float*)d_in[1];
    const float* Wq  = (const float*)d_in[2];
    const float* Wk  = (const float*)d_in[3];
    const float* Wv  = (const float*)d_in[4];
    const float* pW1 = (const float*)d_in[5];
    const float* pb1 = (const float*)d_in[6];
    const float* pW2 = (const float*)d_in[7];
    const float* pb2 = (const float*)d_in[8];
    const float* aW1 = (const float*)d_in[9];
    const float* ab1 = (const float*)d_in[10];
    const float* aW2 = (const float*)d_in[11];
    // d_in[12] = ab2: constant over j -> cancels in per-channel softmax, unused.

    char* ws = (char*)d_ws;
    unsigned char*  bext8 = (unsigned char*)(ws + BEXT8_OFF);
    unsigned char*  aw2f8 = (unsigned char*)(ws + AW2F_OFF);
    unsigned short* pw2f  = (unsigned short*)(ws + PW2F_OFF);
    float*          cArr  = (float*)(ws + CARR_OFF);
    float*          aIa   = (float*)(ws + AI_OFF);
    float*          vPTa  = (float*)(ws + VPT_OFF);
    unsigned short* aJa   = (unsigned short*)(ws + AJ_OFF);
    unsigned char*  kN8a  = (unsigned char*)(ws + KN8_OFF);
    float*          qaA   = (float*)(ws + QA_OFF);

    prep_all<<<1489, 256, 0, stream>>>(x, pos, Wq, Wk, Wv, pW1, pb1, pW2, pb2, aW1, ab1, aW2,
                                       bext8, aw2f8, pw2f, cArr, kN8a, vPTa, aIa, aJa, qaA);
    ptl_main<<<NPTS, 256, 0, stream>>>(aIa, aJa, kN8a, vPTa, bext8, aw2f8, pw2f, cArr, qaA,
                                       (float*)d_out);
}